// Round 6
// baseline (286.465 us; speedup 1.0000x reference)
//
#include <hip/hip_runtime.h>

#define NN_NODES 100000
#define NN_EDGES 50000
#define DD 128
#define NNZP 1600000
#define NT_SEG (NN_EDGES + NN_NODES)   // 150000 segments (edges first, then nodes)
#define TOTP (2 * NNZP)                // 3.2M (seg,val) pairs across both directions
#define BKT_SHIFT 9                    // 512 segments per bucket
#define NBKT ((NT_SEG + 511) / 512)    // 293
#define TILE 8192
#define SMAX 18432
#define PBLK 2048                      // parallel blocks per k_prep branch

typedef unsigned int uint;
typedef unsigned short ushort;
typedef __attribute__((ext_vector_type(8))) short bf16x8;
typedef __attribute__((ext_vector_type(4))) float f32x4;

__device__ __forceinline__ float bf_lo(uint u) {
  union { uint i; float f; } c; c.i = u << 16; return c.f;
}
__device__ __forceinline__ float bf_hi(uint u) {
  union { uint i; float f; } c; c.i = u & 0xffff0000u; return c.f;
}
__device__ __forceinline__ ushort f2bf(float f) {   // round-to-nearest-even
  union { float f; uint i; } c; c.f = f;
  uint r = c.i + 0x7fffu + ((c.i >> 16) & 1u);
  return (ushort)(r >> 16);
}

// ---------- exclusive block scan over 512 ints, 512 threads ----------
__device__ __forceinline__ void block_excl_scan_512(const int* __restrict__ arr,
                                                    int* __restrict__ out,
                                                    int* __restrict__ wsum) {
  int t = threadIdx.x;
  int v = arr[t];
  int lane = t & 63, wid = t >> 6;
  int s = v;
  #pragma unroll
  for (int o = 1; o < 64; o <<= 1) {
    int u = __shfl_up(s, o, 64);
    if (lane >= o) s += u;
  }
  if (lane == 63) wsum[wid] = s;
  __syncthreads();
  int add = 0;
  for (int w = 0; w < wid; ++w) add += wsum[w];
  out[t] = s + add - v;
}

// ---------- Wc = W1@W2 (bf16, transposed [c][k]) and bc = b1@W2 + b2 ----------
__global__ __launch_bounds__(256) void k_wc(const float* __restrict__ W1,
                                            const float* __restrict__ W2,
                                            const float* __restrict__ b1,
                                            const float* __restrict__ b2,
                                            ushort* __restrict__ Wct,
                                            float* __restrict__ bc) {
  __shared__ float sW2[DD * DD];   // 64 KB
  __shared__ float sW1[8 * DD];    // 4 KB
  const int b = blockIdx.x;        // 16 blocks, W1-rows [8b, 8b+8)
  for (int i = threadIdx.x; i < DD * 32; i += 256)
    reinterpret_cast<float4*>(sW2)[i] = reinterpret_cast<const float4*>(W2)[i];
  for (int i = threadIdx.x; i < 8 * 32; i += 256)
    reinterpret_cast<float4*>(sW1)[i] = reinterpret_cast<const float4*>(W1 + b * 8 * DD)[i];
  __syncthreads();
  const int lr = threadIdx.x >> 5;          // 0..7 local row
  const int cg = threadIdx.x & 31;          // col group (4 cols)
  float s0 = 0.f, s1 = 0.f, s2 = 0.f, s3 = 0.f;
  for (int k = 0; k < DD; ++k) {
    float a = sW1[lr * DD + k];
    float4 w = reinterpret_cast<const float4*>(sW2)[k * 32 + cg];
    s0 += a * w.x; s1 += a * w.y; s2 += a * w.z; s3 += a * w.w;
  }
  const int grow = b * 8 + lr;              // k-index in Wct[c][k]
  const int c0 = cg * 4;
  Wct[(size_t)(c0 + 0) * DD + grow] = f2bf(s0);
  Wct[(size_t)(c0 + 1) * DD + grow] = f2bf(s1);
  Wct[(size_t)(c0 + 2) * DD + grow] = f2bf(s2);
  Wct[(size_t)(c0 + 3) * DD + grow] = f2bf(s3);
  if (b == 0 && threadIdx.x < DD) {
    float s = b2[threadIdx.x];
    for (int k = 0; k < DD; ++k) s += b1[k] * sW2[k * DD + threadIdx.x];
    bc[threadIdx.x] = s;
  }
}

// ---------- fused: bucket histogram (2048 blocks) + X->bf16 (2048 blocks) ----------
__global__ __launch_bounds__(256) void k_prep(const float* __restrict__ X,
                                              const int* __restrict__ ninc,
                                              const int* __restrict__ einc,
                                              ushort* __restrict__ Xb,
                                              int* __restrict__ bktcnt) {
  const int b = blockIdx.x;
  if (b < PBLK) {
    __shared__ int h[512];
    for (int t = threadIdx.x; t < 512; t += 256) h[t] = 0;
    __syncthreads();
    const int stride = PBLK * 256;
    for (int i = b * 256 + threadIdx.x; i < TOTP; i += stride) {
      int seg = (i < NNZP) ? einc[i] : (NN_EDGES + ninc[i - NNZP]);
      atomicAdd(&h[seg >> BKT_SHIFT], 1);
    }
    __syncthreads();
    for (int t = threadIdx.x; t < NBKT; t += 256)
      if (h[t]) atomicAdd(&bktcnt[t], h[t]);
  } else {
    const int stride = PBLK * 256;
    for (int i = (b - PBLK) * 256 + threadIdx.x; i < NN_NODES * DD / 4; i += stride) {
      float4 v = reinterpret_cast<const float4*>(X)[i];
      ushort4 o;
      o.x = f2bf(v.x); o.y = f2bf(v.y); o.z = f2bf(v.z); o.w = f2bf(v.w);
      reinterpret_cast<ushort4*>(Xb)[i] = o;
    }
  }
}

// ---------- bucket base scan (1 block, 512 threads) ----------
__global__ void k_bscan(const int* __restrict__ bktcnt, int* __restrict__ bktbase,
                        int* __restrict__ bktcur, int* __restrict__ offs) {
  __shared__ int arr[512], out[512], wsum[8];
  int t = threadIdx.x;
  arr[t] = (t < NBKT) ? bktcnt[t] : 0;
  __syncthreads();
  block_excl_scan_512(arr, out, wsum);
  __syncthreads();
  bktbase[t] = out[t];
  bktcur[t] = out[t];
  if (t == 0) offs[NT_SEG] = TOTP;
}

// ---------- bin pairs into coarse buckets, single global read, coalesced runs ----------
__global__ __launch_bounds__(512) void k_bin(const int* __restrict__ ninc,
                                             const int* __restrict__ einc,
                                             int* __restrict__ bktcur,
                                             int* __restrict__ bval,
                                             ushort* __restrict__ blow) {
  __shared__ int sval[TILE];
  __shared__ ushort slow[TILE], sbkt[TILE];
  __shared__ int bhist[512], bexcl[512], bcur[512], brun[512], wsum[8];
  const int t = threadIdx.x;
  const int i0 = blockIdx.x * TILE;
  const int V = min(TILE, TOTP - i0);
  int pseg[16], pval[16];
  bhist[t] = 0;
  __syncthreads();
  #pragma unroll
  for (int j = 0; j < 16; ++j) {
    int e = t + j * 512;
    if (e < V) {
      int i = i0 + e;
      int seg, val;
      if (i < NNZP) { seg = einc[i]; val = ninc[i]; }
      else          { seg = NN_EDGES + ninc[i - NNZP]; val = einc[i - NNZP]; }
      pseg[j] = seg; pval[j] = val;
      atomicAdd(&bhist[seg >> BKT_SHIFT], 1);
    }
  }
  __syncthreads();
  block_excl_scan_512(bhist, bexcl, wsum);
  __syncthreads();
  if (t < NBKT && bhist[t] > 0) brun[t] = atomicAdd(&bktcur[t], bhist[t]);
  bcur[t] = bexcl[t];
  __syncthreads();
  #pragma unroll
  for (int j = 0; j < 16; ++j) {
    int e = t + j * 512;
    if (e < V) {
      int bk = pseg[j] >> BKT_SHIFT;
      int slot = atomicAdd(&bcur[bk], 1);
      sval[slot] = pval[j];
      slow[slot] = (ushort)(pseg[j] & 511);
      sbkt[slot] = (ushort)bk;
    }
  }
  __syncthreads();
  for (int e = t; e < V; e += 512) {
    int bk = sbkt[e];
    int gpos = brun[bk] + (e - bexcl[bk]);
    bval[gpos] = sval[e];
    blow[gpos] = slow[e];
  }
}

// ---------- per-bucket placement: builds offs + final sorted list ----------
__global__ __launch_bounds__(512) void k_place(const int* __restrict__ bktbase,
                                               const int* __restrict__ bval,
                                               const ushort* __restrict__ blow,
                                               int* __restrict__ offs,
                                               int* __restrict__ list) {
  __shared__ int shist[512], sexcl[512], scur[512], wsum[8];
  __shared__ int stage[SMAX];
  const int b = blockIdx.x;
  const int t = threadIdx.x;
  const int base = bktbase[b];
  const int s = bktbase[b + 1] - base;
  shist[t] = 0;
  __syncthreads();
  for (int e = t; e < s; e += 512) atomicAdd(&shist[blow[base + e]], 1);
  __syncthreads();
  block_excl_scan_512(shist, sexcl, wsum);
  __syncthreads();
  int seg = (b << BKT_SHIFT) + t;
  if (seg < NT_SEG) offs[seg] = base + sexcl[t];
  scur[t] = sexcl[t];
  __syncthreads();
  if (s <= SMAX) {
    for (int e = t; e < s; e += 512) {
      int slot = atomicAdd(&scur[blow[base + e]], 1);
      stage[slot] = bval[base + e];
    }
    __syncthreads();
    for (int e = t; e < s; e += 512) list[base + e] = stage[e];
  } else {
    for (int e = t; e < s; e += 512) {
      int r = atomicAdd(&scur[blow[base + e]], 1);
      list[base + r] = bval[base + e];
    }
  }
}

// ---------- segment mean gather, bf16 rows, 16 lanes/seg, guard-free 8-deep ----------
#define ACC8(V) do { \
    acc[0] += bf_lo(V.x); acc[1] += bf_hi(V.x); \
    acc[2] += bf_lo(V.y); acc[3] += bf_hi(V.y); \
    acc[4] += bf_lo(V.z); acc[5] += bf_hi(V.z); \
    acc[6] += bf_lo(V.w); acc[7] += bf_hi(V.w); } while (0)

__global__ __launch_bounds__(256) void k_agg(const ushort* __restrict__ src,
                                             ushort* __restrict__ dst,
                                             const int* __restrict__ offs,
                                             const int* __restrict__ list,
                                             int nseg, int segbase) {
  int g = (int)((blockIdx.x * blockDim.x + threadIdx.x) >> 4);
  int t = threadIdx.x & 15;
  if (g >= nseg) return;
  int b0 = offs[segbase + g];
  int deg = offs[segbase + g + 1] - b0;
  float acc[8];
  #pragma unroll
  for (int j = 0; j < 8; ++j) acc[j] = 0.f;
  int chunk = 0;
  for (; chunk + 16 <= deg; chunk += 16) {
    int myidx = list[b0 + chunk + t];
    uint4 vb[8];
    #pragma unroll
    for (int j = 0; j < 8; ++j) {
      int id = __shfl(myidx, j, 16);
      vb[j] = reinterpret_cast<const uint4*>(src + (size_t)id * DD)[t];
    }
    #pragma unroll
    for (int j = 0; j < 8; ++j) ACC8(vb[j]);
    #pragma unroll
    for (int j = 0; j < 8; ++j) {
      int id = __shfl(myidx, 8 + j, 16);
      vb[j] = reinterpret_cast<const uint4*>(src + (size_t)id * DD)[t];
    }
    #pragma unroll
    for (int j = 0; j < 8; ++j) ACC8(vb[j]);
  }
  int rem = deg - chunk;
  if (rem > 0) {
    int myidx = (t < rem) ? list[b0 + chunk + t] : 0;
    for (int m = 0; m < rem; ++m) {
      int id = __shfl(myidx, m, 16);
      uint4 v = reinterpret_cast<const uint4*>(src + (size_t)id * DD)[t];
      ACC8(v);
    }
  }
  float inv = 1.0f / fmaxf((float)deg, 1.0f);
  uint4 o;
  o.x = (uint)f2bf(acc[0] * inv) | ((uint)f2bf(acc[1] * inv) << 16);
  o.y = (uint)f2bf(acc[2] * inv) | ((uint)f2bf(acc[3] * inv) << 16);
  o.z = (uint)f2bf(acc[4] * inv) | ((uint)f2bf(acc[5] * inv) << 16);
  o.w = (uint)f2bf(acc[6] * inv) | ((uint)f2bf(acc[7] * inv) << 16);
  reinterpret_cast<uint4*>(dst + (size_t)g * DD)[t] = o;
}

// ---------- MFMA bf16 GEMM: C[M,128] = A[M,128] @ W + gated bias, opt relu ----------
template<int RELU, int CBF16>
__global__ __launch_bounds__(256) void k_gemm_mfma(
    const ushort* __restrict__ A, void* __restrict__ Cv,
    const ushort* __restrict__ Wt, const float* __restrict__ bias,
    const int* __restrict__ segoff, int M) {
  __shared__ ushort sA[DD * DD];   // 32 KB, XOR-swizzled rows (256 B each)
  __shared__ ushort sW[DD * DD];   // 32 KB, rows = output col, XOR-swizzled
  const int tid = threadIdx.x;
  const int R = blockIdx.x * DD;
  const int rows = min(DD, M - R);
  for (int i = tid; i < DD * 16; i += 256) {
    int r = i >> 4, c8 = i & 15;
    uint4 v = reinterpret_cast<const uint4*>(Wt + (size_t)r * DD)[c8];
    int bo = (c8 * 16) ^ ((r & 7) << 4);
    *reinterpret_cast<uint4*>(reinterpret_cast<char*>(sW) + r * 256 + bo) = v;
  }
  for (int i = tid; i < DD * 16; i += 256) {
    int r = i >> 4, c8 = i & 15;
    uint4 v = make_uint4(0u, 0u, 0u, 0u);
    if (r < rows) v = reinterpret_cast<const uint4*>(A + (size_t)(R + r) * DD)[c8];
    int bo = (c8 * 16) ^ ((r & 7) << 4);
    *reinterpret_cast<uint4*>(reinterpret_cast<char*>(sA) + r * 256 + bo) = v;
  }
  __syncthreads();
  const int wid = tid >> 6;
  const int l = tid & 63;
  const int lr = l & 15;
  const int lg = l >> 4;
  const int wrow = wid * 32;
  f32x4 acc[2][8];
  #pragma unroll
  for (int a = 0; a < 2; ++a)
    #pragma unroll
    for (int b = 0; b < 8; ++b) acc[a][b] = (f32x4){0.f, 0.f, 0.f, 0.f};
  const char* cA = reinterpret_cast<const char*>(sA);
  const char* cW = reinterpret_cast<const char*>(sW);
  #pragma unroll
  for (int k0 = 0; k0 < 4; ++k0) {
    int kb = k0 * 64 + lg * 16;
    int r0 = wrow + lr, r1 = wrow + 16 + lr;
    bf16x8 a0 = *reinterpret_cast<const bf16x8*>(cA + r0 * 256 + (kb ^ ((r0 & 7) << 4)));
    bf16x8 a1 = *reinterpret_cast<const bf16x8*>(cA + r1 * 256 + (kb ^ ((r1 & 7) << 4)));
    bf16x8 bfr[8];
    #pragma unroll
    for (int ct = 0; ct < 8; ++ct) {
      int c = ct * 16 + lr;
      bfr[ct] = *reinterpret_cast<const bf16x8*>(cW + c * 256 + (kb ^ ((c & 7) << 4)));
    }
    #pragma unroll
    for (int ct = 0; ct < 8; ++ct) {
      acc[0][ct] = __builtin_amdgcn_mfma_f32_16x16x32_bf16(a0, bfr[ct], acc[0][ct], 0, 0, 0);
      acc[1][ct] = __builtin_amdgcn_mfma_f32_16x16x32_bf16(a1, bfr[ct], acc[1][ct], 0, 0, 0);
    }
  }
  float bcol[8];
  #pragma unroll
  for (int ct = 0; ct < 8; ++ct) bcol[ct] = bias[ct * 16 + lr];
  #pragma unroll
  for (int rt = 0; rt < 2; ++rt) {
    #pragma unroll
    for (int j = 0; j < 4; ++j) {
      int r = wrow + rt * 16 + lg * 4 + j;
      if (r < rows) {
        int gr = R + r;
        float flag = (segoff[gr + 1] > segoff[gr]) ? 1.f : 0.f;
        #pragma unroll
        for (int ct = 0; ct < 8; ++ct) {
          float v = acc[rt][ct][j] + bcol[ct] * flag;
          if (RELU) v = fmaxf(v, 0.f);
          if (CBF16)
            reinterpret_cast<ushort*>(Cv)[(size_t)gr * DD + ct * 16 + lr] = f2bf(v);
          else
            reinterpret_cast<float*>(Cv)[(size_t)gr * DD + ct * 16 + lr] = v;
        }
      }
    }
  }
}

extern "C" void kernel_launch(void* const* d_in, const int* in_sizes, int n_in,
                              void* d_out, int out_size, void* d_ws, size_t ws_size,
                              hipStream_t stream) {
  const float* X   = (const float*)d_in[1];
  const int*   inc = (const int*)d_in[2];
  const float* W1  = (const float*)d_in[3];
  const float* b1  = (const float*)d_in[4];
  const float* W2  = (const float*)d_in[5];
  const float* b2  = (const float*)d_in[6];
  float* out = (float*)d_out;
  const int* ninc = inc;
  const int* einc = inc + NNZP;

  // workspace carve-up (~78 MB)
  char* wsp = (char*)d_ws;
  ushort* bufE = (ushort*)wsp; wsp += (size_t)NN_EDGES * DD * sizeof(ushort);  // 12.8 MB (E = edge means)
  ushort* bufN = (ushort*)wsp; wsp += (size_t)NN_NODES * DD * sizeof(ushort);  // 25.6 MB (P = node means)
  ushort* Xb   = (ushort*)wsp; wsp += (size_t)NN_NODES * DD * sizeof(ushort);  // 25.6 MB X bf16
  int* offs    = (int*)wsp;    wsp += (size_t)(NT_SEG + 1) * sizeof(int);
  int* list    = (int*)wsp;    wsp += (size_t)TOTP * sizeof(int);              // 12.8 MB
  int* bktcnt  = (int*)wsp;    wsp += 512 * sizeof(int);
  int* bktbase = (int*)wsp;    wsp += 512 * sizeof(int);
  int* bktcur  = (int*)wsp;    wsp += 512 * sizeof(int);
  ushort* Wct  = (ushort*)wsp; wsp += (size_t)DD * DD * sizeof(ushort);        // 32 KB
  float* bc    = (float*)wsp;  wsp += DD * sizeof(float);
  // sort staging aliased into bufN (dead before agg2 writes node means)
  int* bval = (int*)bufN;                                                      // 12.8 MB
  ushort* blow = (ushort*)((char*)bufN + (size_t)TOTP * sizeof(int));          // 6.4 MB

  hipMemsetAsync(bktcnt, 0, 512 * sizeof(int), stream);

  // Wc = W1@W2 (bf16 [c][k]), bc = b1@W2 + b2
  k_wc<<<16, 256, 0, stream>>>(W1, W2, b1, b2, Wct, bc);
  // fused bucket-hist (2048 blocks) + X->bf16 (2048 blocks)
  k_prep<<<2 * PBLK, 256, 0, stream>>>(X, ninc, einc, Xb, bktcnt);
  k_bscan<<<1, 512, 0, stream>>>(bktcnt, bktbase, bktcur, offs);
  k_bin<<<(TOTP + TILE - 1) / TILE, 512, 0, stream>>>(ninc, einc, bktcur, bval, blow);
  k_place<<<NBKT, 512, 0, stream>>>(bktbase, bval, blow, offs, list);

  // E[e] = mean_{n in e} Xb[n]  (bf16)
  k_agg<<<(NN_EDGES * 16 + 255) / 256, 256, 0, stream>>>(Xb, bufE, offs, list, NN_EDGES, 0);
  // P[n] = mean_{e ni n} E[e]   (bf16)
  k_agg<<<(NN_NODES * 16 + 255) / 256, 256, 0, stream>>>(bufE, bufN, offs, list, NN_NODES, NN_EDGES);
  // out = relu(P @ Wc + bc (deg-gated)), fp32 to d_out, MFMA
  k_gemm_mfma<1, 0><<<(NN_NODES + DD - 1) / DD, 256, 0, stream>>>(bufN, out, Wct, bc, offs + NN_EDGES, NN_NODES);
}

// Round 7
// 220.755 us; speedup vs baseline: 1.2977x; 1.2977x over previous
//
#include <hip/hip_runtime.h>

#define NN_NODES 100000
#define NN_EDGES 50000
#define DD 128
#define NNZP 1600000
#define NT_SEG (NN_EDGES + NN_NODES)   // 150000 segments (edges first, then nodes)
#define TOTP (2 * NNZP)                // 3.2M (seg,val) pairs across both directions
#define BKT_SHIFT 9                    // 512 segments per bucket
#define NBKT ((NT_SEG + 511) / 512)    // 293
#define TILE 8192
#define NBIN ((TOTP + TILE - 1) / TILE)  // 391
#define CVTBLK 1024
#define SMAX 18432
#define CAP 20480                      // fixed bucket staging capacity (~32 sigma margin)

typedef unsigned int uint;
typedef unsigned short ushort;
typedef __attribute__((ext_vector_type(8))) short bf16x8;
typedef __attribute__((ext_vector_type(4))) float f32x4;

__device__ __forceinline__ float bf_lo(uint u) {
  union { uint i; float f; } c; c.i = u << 16; return c.f;
}
__device__ __forceinline__ float bf_hi(uint u) {
  union { uint i; float f; } c; c.i = u & 0xffff0000u; return c.f;
}
__device__ __forceinline__ ushort f2bf(float f) {   // round-to-nearest-even
  union { float f; uint i; } c; c.f = f;
  uint r = c.i + 0x7fffu + ((c.i >> 16) & 1u);
  return (ushort)(r >> 16);
}

// ---------- exclusive block scan over 512 ints, 512 threads ----------
__device__ __forceinline__ void block_excl_scan_512(const int* __restrict__ arr,
                                                    int* __restrict__ out,
                                                    int* __restrict__ wsum) {
  int t = threadIdx.x;
  int v = arr[t];
  int lane = t & 63, wid = t >> 6;
  int s = v;
  #pragma unroll
  for (int o = 1; o < 64; o <<= 1) {
    int u = __shfl_up(s, o, 64);
    if (lane >= o) s += u;
  }
  if (lane == 63) wsum[wid] = s;
  __syncthreads();
  int add = 0;
  for (int w = 0; w < wid; ++w) add += wsum[w];
  out[t] = s + add - v;
}

// ---------- Wc = W1@W2 (bf16, transposed [c][k]) and bc = b1@W2 + b2 ----------
__global__ __launch_bounds__(256) void k_wc(const float* __restrict__ W1,
                                            const float* __restrict__ W2,
                                            const float* __restrict__ b1,
                                            const float* __restrict__ b2,
                                            ushort* __restrict__ Wct,
                                            float* __restrict__ bc) {
  __shared__ float sW2[DD * DD];   // 64 KB
  __shared__ float sW1[8 * DD];    // 4 KB
  const int b = blockIdx.x;        // 16 blocks, W1-rows [8b, 8b+8)
  for (int i = threadIdx.x; i < DD * 32; i += 256)
    reinterpret_cast<float4*>(sW2)[i] = reinterpret_cast<const float4*>(W2)[i];
  for (int i = threadIdx.x; i < 8 * 32; i += 256)
    reinterpret_cast<float4*>(sW1)[i] = reinterpret_cast<const float4*>(W1 + b * 8 * DD)[i];
  __syncthreads();
  const int lr = threadIdx.x >> 5;          // 0..7 local row
  const int cg = threadIdx.x & 31;          // col group (4 cols)
  float s0 = 0.f, s1 = 0.f, s2 = 0.f, s3 = 0.f;
  for (int k = 0; k < DD; ++k) {
    float a = sW1[lr * DD + k];
    float4 w = reinterpret_cast<const float4*>(sW2)[k * 32 + cg];
    s0 += a * w.x; s1 += a * w.y; s2 += a * w.z; s3 += a * w.w;
  }
  const int grow = b * 8 + lr;              // k-index in Wct[c][k]
  const int c0 = cg * 4;
  Wct[(size_t)(c0 + 0) * DD + grow] = f2bf(s0);
  Wct[(size_t)(c0 + 1) * DD + grow] = f2bf(s1);
  Wct[(size_t)(c0 + 2) * DD + grow] = f2bf(s2);
  Wct[(size_t)(c0 + 3) * DD + grow] = f2bf(s3);
  if (b == 0 && threadIdx.x < DD) {
    float s = b2[threadIdx.x];
    for (int k = 0; k < DD; ++k) s += b1[k] * sW2[k * DD + threadIdx.x];
    bc[threadIdx.x] = s;
  }
}

// ---------- bin pairs into fixed-capacity bucket staging + fused X->bf16 ----------
__global__ __launch_bounds__(512) void k_bin(const int* __restrict__ ninc,
                                             const int* __restrict__ einc,
                                             int* __restrict__ bktcur,
                                             int* __restrict__ bval,
                                             ushort* __restrict__ blow,
                                             const float* __restrict__ X,
                                             ushort* __restrict__ Xb) {
  const int b = blockIdx.x;
  if (b >= NBIN) {
    // fused X->bf16 convert branch (no syncthreads here)
    const int stride = CVTBLK * 512;
    for (int i = (b - NBIN) * 512 + threadIdx.x; i < NN_NODES * DD / 4; i += stride) {
      float4 v = reinterpret_cast<const float4*>(X)[i];
      ushort4 o;
      o.x = f2bf(v.x); o.y = f2bf(v.y); o.z = f2bf(v.z); o.w = f2bf(v.w);
      reinterpret_cast<ushort4*>(Xb)[i] = o;
    }
    return;
  }
  __shared__ int sval[TILE];
  __shared__ ushort slow[TILE], sbkt[TILE];
  __shared__ int bhist[512], bexcl[512], bcur[512], brun[512], wsum[8];
  const int t = threadIdx.x;
  const int i0 = b * TILE;
  const int V = min(TILE, TOTP - i0);
  int pseg[16], pval[16];
  bhist[t] = 0;
  __syncthreads();
  #pragma unroll
  for (int j = 0; j < 16; ++j) {
    int e = t + j * 512;
    if (e < V) {
      int i = i0 + e;
      int seg, val;
      if (i < NNZP) { seg = einc[i]; val = ninc[i]; }
      else          { seg = NN_EDGES + ninc[i - NNZP]; val = einc[i - NNZP]; }
      pseg[j] = seg; pval[j] = val;
      atomicAdd(&bhist[seg >> BKT_SHIFT], 1);
    }
  }
  __syncthreads();
  block_excl_scan_512(bhist, bexcl, wsum);
  __syncthreads();
  // reserve run in this bucket's fixed-cap staging region
  if (t < NBKT && bhist[t] > 0)
    brun[t] = t * CAP + atomicAdd(&bktcur[t], bhist[t]);
  bcur[t] = bexcl[t];
  __syncthreads();
  #pragma unroll
  for (int j = 0; j < 16; ++j) {
    int e = t + j * 512;
    if (e < V) {
      int bk = pseg[j] >> BKT_SHIFT;
      int slot = atomicAdd(&bcur[bk], 1);
      sval[slot] = pval[j];
      slow[slot] = (ushort)(pseg[j] & 511);
      sbkt[slot] = (ushort)bk;
    }
  }
  __syncthreads();
  for (int e = t; e < V; e += 512) {
    int bk = sbkt[e];
    int gpos = brun[bk] + (e - bexcl[bk]);
    if (gpos < (bk + 1) * CAP) {      // OOB guard (statistically unreachable)
      bval[gpos] = sval[e];
      blow[gpos] = slow[e];
    }
  }
}

// ---------- bucket base scan from measured counts (1 block, 512 threads) ----------
__global__ void k_bscan(const int* __restrict__ bktcnt, int* __restrict__ bktbase,
                        int* __restrict__ offs) {
  __shared__ int arr[512], out[512], wsum[8];
  int t = threadIdx.x;
  arr[t] = (t < NBKT) ? min(bktcnt[t], CAP) : 0;
  __syncthreads();
  block_excl_scan_512(arr, out, wsum);
  __syncthreads();
  bktbase[t] = out[t];
  if (t == 0) offs[NT_SEG] = TOTP;
}

// ---------- per-bucket placement: builds offs + final sorted list ----------
__global__ __launch_bounds__(512) void k_place(const int* __restrict__ bktbase,
                                               const int* __restrict__ bktcnt,
                                               const int* __restrict__ bval,
                                               const ushort* __restrict__ blow,
                                               int* __restrict__ offs,
                                               int* __restrict__ list) {
  __shared__ int shist[512], sexcl[512], scur[512], wsum[8];
  __shared__ int stage[SMAX];
  const int b = blockIdx.x;
  const int t = threadIdx.x;
  const int base = bktbase[b];
  const int sb = b * CAP;               // staging base
  const int s = min(bktcnt[b], CAP);
  shist[t] = 0;
  __syncthreads();
  for (int e = t; e < s; e += 512) atomicAdd(&shist[blow[sb + e]], 1);
  __syncthreads();
  block_excl_scan_512(shist, sexcl, wsum);
  __syncthreads();
  int seg = (b << BKT_SHIFT) + t;
  if (seg < NT_SEG) offs[seg] = base + sexcl[t];
  scur[t] = sexcl[t];
  __syncthreads();
  if (s <= SMAX) {
    for (int e = t; e < s; e += 512) {
      int slot = atomicAdd(&scur[blow[sb + e]], 1);
      stage[slot] = bval[sb + e];
    }
    __syncthreads();
    for (int e = t; e < s; e += 512) list[base + e] = stage[e];
  } else {
    for (int e = t; e < s; e += 512) {
      int r = atomicAdd(&scur[blow[sb + e]], 1);
      list[base + r] = bval[sb + e];
    }
  }
}

// ---------- segment mean gather, bf16 rows, 16 lanes/seg, guard-free 8-deep ----------
// MODE 0: write bf16 row. MODE 1: fused epilogue — +bias*gate, relu, fp32 row out.
#define ACC8(V) do { \
    acc[0] += bf_lo(V.x); acc[1] += bf_hi(V.x); \
    acc[2] += bf_lo(V.y); acc[3] += bf_hi(V.y); \
    acc[4] += bf_lo(V.z); acc[5] += bf_hi(V.z); \
    acc[6] += bf_lo(V.w); acc[7] += bf_hi(V.w); } while (0)

template<int MODE>
__global__ __launch_bounds__(256) void k_agg(const ushort* __restrict__ src,
                                             void* __restrict__ dstv,
                                             const float* __restrict__ bias,
                                             const int* __restrict__ offs,
                                             const int* __restrict__ list,
                                             int nseg, int segbase) {
  int g = (int)((blockIdx.x * blockDim.x + threadIdx.x) >> 4);
  int t = threadIdx.x & 15;
  if (g >= nseg) return;
  int b0 = offs[segbase + g];
  int deg = offs[segbase + g + 1] - b0;
  float acc[8];
  #pragma unroll
  for (int j = 0; j < 8; ++j) acc[j] = 0.f;
  int chunk = 0;
  for (; chunk + 16 <= deg; chunk += 16) {
    int myidx = list[b0 + chunk + t];
    uint4 vb[8];
    #pragma unroll
    for (int j = 0; j < 8; ++j) {
      int id = __shfl(myidx, j, 16);
      vb[j] = reinterpret_cast<const uint4*>(src + (size_t)id * DD)[t];
    }
    #pragma unroll
    for (int j = 0; j < 8; ++j) ACC8(vb[j]);
    #pragma unroll
    for (int j = 0; j < 8; ++j) {
      int id = __shfl(myidx, 8 + j, 16);
      vb[j] = reinterpret_cast<const uint4*>(src + (size_t)id * DD)[t];
    }
    #pragma unroll
    for (int j = 0; j < 8; ++j) ACC8(vb[j]);
  }
  int rem = deg - chunk;
  if (rem > 0) {
    int myidx = (t < rem) ? list[b0 + chunk + t] : 0;
    for (int m = 0; m < rem; ++m) {
      int id = __shfl(myidx, m, 16);
      uint4 v = reinterpret_cast<const uint4*>(src + (size_t)id * DD)[t];
      ACC8(v);
    }
  }
  float inv = 1.0f / fmaxf((float)deg, 1.0f);
  if (MODE == 0) {
    ushort* dst = (ushort*)dstv;
    uint4 o;
    o.x = (uint)f2bf(acc[0] * inv) | ((uint)f2bf(acc[1] * inv) << 16);
    o.y = (uint)f2bf(acc[2] * inv) | ((uint)f2bf(acc[3] * inv) << 16);
    o.z = (uint)f2bf(acc[4] * inv) | ((uint)f2bf(acc[5] * inv) << 16);
    o.w = (uint)f2bf(acc[6] * inv) | ((uint)f2bf(acc[7] * inv) << 16);
    reinterpret_cast<uint4*>(dst + (size_t)g * DD)[t] = o;
  } else {
    float flag = (deg > 0) ? 1.f : 0.f;
    float4 bb0 = reinterpret_cast<const float4*>(bias)[2 * t];
    float4 bb1 = reinterpret_cast<const float4*>(bias)[2 * t + 1];
    float4 o0, o1;
    o0.x = fmaxf(acc[0] * inv + bb0.x * flag, 0.f);
    o0.y = fmaxf(acc[1] * inv + bb0.y * flag, 0.f);
    o0.z = fmaxf(acc[2] * inv + bb0.z * flag, 0.f);
    o0.w = fmaxf(acc[3] * inv + bb0.w * flag, 0.f);
    o1.x = fmaxf(acc[4] * inv + bb1.x * flag, 0.f);
    o1.y = fmaxf(acc[5] * inv + bb1.y * flag, 0.f);
    o1.z = fmaxf(acc[6] * inv + bb1.z * flag, 0.f);
    o1.w = fmaxf(acc[7] * inv + bb1.w * flag, 0.f);
    float* orow = (float*)dstv + (size_t)g * DD;
    reinterpret_cast<float4*>(orow)[2 * t] = o0;
    reinterpret_cast<float4*>(orow)[2 * t + 1] = o1;
  }
}

// ---------- MFMA bf16 GEMM: C[M,128] = A[M,128] @ W (+ gated bias, relu) ----------
template<int RELU, int CBF16, int BIASED>
__global__ __launch_bounds__(256) void k_gemm_mfma(
    const ushort* __restrict__ A, void* __restrict__ Cv,
    const ushort* __restrict__ Wt, const float* __restrict__ bias,
    const int* __restrict__ segoff, int M) {
  __shared__ ushort sA[DD * DD];   // 32 KB, XOR-swizzled rows (256 B each)
  __shared__ ushort sW[DD * DD];   // 32 KB
  const int tid = threadIdx.x;
  const int R = blockIdx.x * DD;
  const int rows = min(DD, M - R);
  for (int i = tid; i < DD * 16; i += 256) {
    int r = i >> 4, c8 = i & 15;
    uint4 v = reinterpret_cast<const uint4*>(Wt + (size_t)r * DD)[c8];
    int bo = (c8 * 16) ^ ((r & 7) << 4);
    *reinterpret_cast<uint4*>(reinterpret_cast<char*>(sW) + r * 256 + bo) = v;
  }
  for (int i = tid; i < DD * 16; i += 256) {
    int r = i >> 4, c8 = i & 15;
    uint4 v = make_uint4(0u, 0u, 0u, 0u);
    if (r < rows) v = reinterpret_cast<const uint4*>(A + (size_t)(R + r) * DD)[c8];
    int bo = (c8 * 16) ^ ((r & 7) << 4);
    *reinterpret_cast<uint4*>(reinterpret_cast<char*>(sA) + r * 256 + bo) = v;
  }
  __syncthreads();
  const int wid = tid >> 6;
  const int l = tid & 63;
  const int lr = l & 15;
  const int lg = l >> 4;
  const int wrow = wid * 32;
  f32x4 acc[2][8];
  #pragma unroll
  for (int a = 0; a < 2; ++a)
    #pragma unroll
    for (int b = 0; b < 8; ++b) acc[a][b] = (f32x4){0.f, 0.f, 0.f, 0.f};
  const char* cA = reinterpret_cast<const char*>(sA);
  const char* cW = reinterpret_cast<const char*>(sW);
  #pragma unroll
  for (int k0 = 0; k0 < 4; ++k0) {
    int kb = k0 * 64 + lg * 16;
    int r0 = wrow + lr, r1 = wrow + 16 + lr;
    bf16x8 a0 = *reinterpret_cast<const bf16x8*>(cA + r0 * 256 + (kb ^ ((r0 & 7) << 4)));
    bf16x8 a1 = *reinterpret_cast<const bf16x8*>(cA + r1 * 256 + (kb ^ ((r1 & 7) << 4)));
    bf16x8 bfr[8];
    #pragma unroll
    for (int ct = 0; ct < 8; ++ct) {
      int c = ct * 16 + lr;
      bfr[ct] = *reinterpret_cast<const bf16x8*>(cW + c * 256 + (kb ^ ((c & 7) << 4)));
    }
    #pragma unroll
    for (int ct = 0; ct < 8; ++ct) {
      acc[0][ct] = __builtin_amdgcn_mfma_f32_16x16x32_bf16(a0, bfr[ct], acc[0][ct], 0, 0, 0);
      acc[1][ct] = __builtin_amdgcn_mfma_f32_16x16x32_bf16(a1, bfr[ct], acc[1][ct], 0, 0, 0);
    }
  }
  float bcol[8];
  if (BIASED) {
    #pragma unroll
    for (int ct = 0; ct < 8; ++ct) bcol[ct] = bias[ct * 16 + lr];
  }
  #pragma unroll
  for (int rt = 0; rt < 2; ++rt) {
    #pragma unroll
    for (int j = 0; j < 4; ++j) {
      int r = wrow + rt * 16 + lg * 4 + j;
      if (r < rows) {
        int gr = R + r;
        float flag = 0.f;
        if (BIASED) flag = (segoff[gr + 1] > segoff[gr]) ? 1.f : 0.f;
        #pragma unroll
        for (int ct = 0; ct < 8; ++ct) {
          float v = acc[rt][ct][j];
          if (BIASED) v += bcol[ct] * flag;
          if (RELU) v = fmaxf(v, 0.f);
          if (CBF16)
            reinterpret_cast<ushort*>(Cv)[(size_t)gr * DD + ct * 16 + lr] = f2bf(v);
          else
            reinterpret_cast<float*>(Cv)[(size_t)gr * DD + ct * 16 + lr] = v;
        }
      }
    }
  }
}

extern "C" void kernel_launch(void* const* d_in, const int* in_sizes, int n_in,
                              void* d_out, int out_size, void* d_ws, size_t ws_size,
                              hipStream_t stream) {
  const float* X   = (const float*)d_in[1];
  const int*   inc = (const int*)d_in[2];
  const float* W1  = (const float*)d_in[3];
  const float* b1  = (const float*)d_in[4];
  const float* W2  = (const float*)d_in[5];
  const float* b2  = (const float*)d_in[6];
  float* out = (float*)d_out;
  const int* ninc = inc;
  const int* einc = inc + NNZP;

  // workspace carve-up (~75 MB)
  char* wsp = (char*)d_ws;
  int* bval    = (int*)wsp;    wsp += (size_t)NBKT * CAP * sizeof(int);        // 24.0 MB staging vals
  ushort* blow = (ushort*)wsp; wsp += (size_t)NBKT * CAP * sizeof(ushort);     // 12.0 MB staging low9
  ushort* Xb   = (ushort*)wsp; wsp += (size_t)NN_NODES * DD * sizeof(ushort);  // 25.6 MB X bf16
  int* offs    = (int*)wsp;    wsp += (size_t)(NT_SEG + 1) * sizeof(int);      // 0.6 MB
  int* list    = (int*)wsp;    wsp += (size_t)TOTP * sizeof(int);              // 12.8 MB
  int* bktcur  = (int*)wsp;    wsp += 512 * sizeof(int);
  int* bktbase = (int*)wsp;    wsp += 512 * sizeof(int);
  ushort* Wct  = (ushort*)wsp; wsp += (size_t)DD * DD * sizeof(ushort);        // 32 KB
  float* bc    = (float*)wsp;  wsp += DD * sizeof(float);
  // E / E' buffer aliases the head of staging (staging dead after k_place)
  ushort* bufE = (ushort*)bval;                                                // 12.8 MB

  hipMemsetAsync(bktcur, 0, 512 * sizeof(int), stream);

  // Wc = W1@W2 (bf16 [c][k]), bc = b1@W2 + b2
  k_wc<<<16, 256, 0, stream>>>(W1, W2, b1, b2, Wct, bc);
  // bin into fixed-cap staging + fused X->bf16
  k_bin<<<NBIN + CVTBLK, 512, 0, stream>>>(ninc, einc, bktcur, bval, blow, X, Xb);
  // exact bucket bases from measured counts
  k_bscan<<<1, 512, 0, stream>>>(bktcur, bktbase, offs);
  // compact into final CSR (offs + list)
  k_place<<<NBKT, 512, 0, stream>>>(bktbase, bktcur, bval, blow, offs, list);

  // E[e] = mean_{n in e} Xb[n]  (bf16)
  k_agg<0><<<(NN_EDGES * 16 + 255) / 256, 256, 0, stream>>>(Xb, bufE, nullptr, offs, list, NN_EDGES, 0);
  // E' = E @ Wc  (50k rows, in-place bf16, MFMA, no bias)
  k_gemm_mfma<0, 1, 0><<<(NN_EDGES + DD - 1) / DD, 256, 0, stream>>>(bufE, bufE, Wct, nullptr, nullptr, NN_EDGES);
  // out[n] = relu(mean_{e ni n} E'[e] + bc*gate)  (fp32, fused epilogue)
  k_agg<1><<<(NN_NODES * 16 + 255) / 256, 256, 0, stream>>>(bufE, out, bc, offs, list, NN_NODES, NN_EDGES);
}

// Round 8
// 198.481 us; speedup vs baseline: 1.4433x; 1.1122x over previous
//
#include <hip/hip_runtime.h>

#define NN_NODES 100000
#define NN_EDGES 50000
#define DD 128
#define NNZP 1600000
#define NT_SEG (NN_EDGES + NN_NODES)   // 150000 segments (edges first, then nodes)
#define TOTP (2 * NNZP)                // 3.2M (seg,val) pairs across both directions
#define BKT_SHIFT 9                    // 512 segments per bucket
#define NBKT ((NT_SEG + 511) / 512)    // 293
#define TILE 8192
#define NBIN ((TOTP + TILE - 1) / TILE)  // 391
#define CVTBLK 1024
#define SMAX 18432
#define CAP 20480                      // fixed bucket staging capacity (~32 sigma margin)

typedef unsigned int uint;
typedef unsigned short ushort;
typedef __attribute__((ext_vector_type(8))) short bf16x8;
typedef __attribute__((ext_vector_type(4))) float f32x4;

__device__ __forceinline__ float bf_lo(uint u) {
  union { uint i; float f; } c; c.i = u << 16; return c.f;
}
__device__ __forceinline__ float bf_hi(uint u) {
  union { uint i; float f; } c; c.i = u & 0xffff0000u; return c.f;
}
__device__ __forceinline__ ushort f2bf(float f) {   // round-to-nearest-even
  union { float f; uint i; } c; c.f = f;
  uint r = c.i + 0x7fffu + ((c.i >> 16) & 1u);
  return (ushort)(r >> 16);
}

// ---------- exclusive block scan over 512 ints, 512 threads ----------
__device__ __forceinline__ void block_excl_scan_512(const int* __restrict__ arr,
                                                    int* __restrict__ out,
                                                    int* __restrict__ wsum) {
  int t = threadIdx.x;
  int v = arr[t];
  int lane = t & 63, wid = t >> 6;
  int s = v;
  #pragma unroll
  for (int o = 1; o < 64; o <<= 1) {
    int u = __shfl_up(s, o, 64);
    if (lane >= o) s += u;
  }
  if (lane == 63) wsum[wid] = s;
  __syncthreads();
  int add = 0;
  for (int w = 0; w < wid; ++w) add += wsum[w];
  out[t] = s + add - v;
}

// ---------- Wc = W1@W2 (bf16, transposed [c][k]) and bc = b1@W2 + b2 ----------
__global__ __launch_bounds__(256) void k_wc(const float* __restrict__ W1,
                                            const float* __restrict__ W2,
                                            const float* __restrict__ b1,
                                            const float* __restrict__ b2,
                                            ushort* __restrict__ Wct,
                                            float* __restrict__ bc) {
  __shared__ float sW2[DD * DD];   // 64 KB
  __shared__ float sW1[8 * DD];    // 4 KB
  const int b = blockIdx.x;        // 16 blocks, W1-rows [8b, 8b+8)
  for (int i = threadIdx.x; i < DD * 32; i += 256)
    reinterpret_cast<float4*>(sW2)[i] = reinterpret_cast<const float4*>(W2)[i];
  for (int i = threadIdx.x; i < 8 * 32; i += 256)
    reinterpret_cast<float4*>(sW1)[i] = reinterpret_cast<const float4*>(W1 + b * 8 * DD)[i];
  __syncthreads();
  const int lr = threadIdx.x >> 5;          // 0..7 local row
  const int cg = threadIdx.x & 31;          // col group (4 cols)
  float s0 = 0.f, s1 = 0.f, s2 = 0.f, s3 = 0.f;
  for (int k = 0; k < DD; ++k) {
    float a = sW1[lr * DD + k];
    float4 w = reinterpret_cast<const float4*>(sW2)[k * 32 + cg];
    s0 += a * w.x; s1 += a * w.y; s2 += a * w.z; s3 += a * w.w;
  }
  const int grow = b * 8 + lr;              // k-index in Wct[c][k]
  const int c0 = cg * 4;
  Wct[(size_t)(c0 + 0) * DD + grow] = f2bf(s0);
  Wct[(size_t)(c0 + 1) * DD + grow] = f2bf(s1);
  Wct[(size_t)(c0 + 2) * DD + grow] = f2bf(s2);
  Wct[(size_t)(c0 + 3) * DD + grow] = f2bf(s3);
  if (b == 0 && threadIdx.x < DD) {
    float s = b2[threadIdx.x];
    for (int k = 0; k < DD; ++k) s += b1[k] * sW2[k * DD + threadIdx.x];
    bc[threadIdx.x] = s;
  }
}

// ---------- bin pairs into fixed-capacity bucket staging + fused X->bf16 ----------
__global__ __launch_bounds__(512) void k_bin(const int* __restrict__ ninc,
                                             const int* __restrict__ einc,
                                             int* __restrict__ bktcur,
                                             int* __restrict__ bval,
                                             ushort* __restrict__ blow,
                                             const float* __restrict__ X,
                                             ushort* __restrict__ Xb) {
  const int b = blockIdx.x;
  if (b >= NBIN) {
    // fused X->bf16 convert branch (no syncthreads here)
    const int stride = CVTBLK * 512;
    for (int i = (b - NBIN) * 512 + threadIdx.x; i < NN_NODES * DD / 4; i += stride) {
      float4 v = reinterpret_cast<const float4*>(X)[i];
      ushort4 o;
      o.x = f2bf(v.x); o.y = f2bf(v.y); o.z = f2bf(v.z); o.w = f2bf(v.w);
      reinterpret_cast<ushort4*>(Xb)[i] = o;
    }
    return;
  }
  __shared__ int sval[TILE];
  __shared__ ushort slow[TILE], sbkt[TILE];
  __shared__ int bhist[512], bexcl[512], bcur[512], brun[512], wsum[8];
  const int t = threadIdx.x;
  const int i0 = b * TILE;
  const int V = min(TILE, TOTP - i0);
  int pseg[16], pval[16];
  bhist[t] = 0;
  __syncthreads();
  #pragma unroll
  for (int j = 0; j < 16; ++j) {
    int e = t + j * 512;
    if (e < V) {
      int i = i0 + e;
      int seg, val;
      if (i < NNZP) { seg = einc[i]; val = ninc[i]; }
      else          { seg = NN_EDGES + ninc[i - NNZP]; val = einc[i - NNZP]; }
      pseg[j] = seg; pval[j] = val;
      atomicAdd(&bhist[seg >> BKT_SHIFT], 1);
    }
  }
  __syncthreads();
  block_excl_scan_512(bhist, bexcl, wsum);
  __syncthreads();
  // reserve run in this bucket's fixed-cap staging region
  if (t < NBKT && bhist[t] > 0)
    brun[t] = t * CAP + atomicAdd(&bktcur[t], bhist[t]);
  bcur[t] = bexcl[t];
  __syncthreads();
  #pragma unroll
  for (int j = 0; j < 16; ++j) {
    int e = t + j * 512;
    if (e < V) {
      int bk = pseg[j] >> BKT_SHIFT;
      int slot = atomicAdd(&bcur[bk], 1);
      sval[slot] = pval[j];
      slow[slot] = (ushort)(pseg[j] & 511);
      sbkt[slot] = (ushort)bk;
    }
  }
  __syncthreads();
  for (int e = t; e < V; e += 512) {
    int bk = sbkt[e];
    int gpos = brun[bk] + (e - bexcl[bk]);
    if (gpos < (bk + 1) * CAP) {      // OOB guard (statistically unreachable)
      bval[gpos] = sval[e];
      blow[gpos] = slow[e];
    }
  }
}

// ---------- bucket base scan from measured counts (1 block, 512 threads) ----------
__global__ void k_bscan(const int* __restrict__ bktcnt, int* __restrict__ bktbase,
                        int* __restrict__ offs) {
  __shared__ int arr[512], out[512], wsum[8];
  int t = threadIdx.x;
  arr[t] = (t < NBKT) ? min(bktcnt[t], CAP) : 0;
  __syncthreads();
  block_excl_scan_512(arr, out, wsum);
  __syncthreads();
  bktbase[t] = out[t];
  if (t == 0) offs[NT_SEG] = TOTP;
}

// ---------- per-bucket placement: builds offs + final sorted list ----------
__global__ __launch_bounds__(512) void k_place(const int* __restrict__ bktbase,
                                               const int* __restrict__ bktcnt,
                                               const int* __restrict__ bval,
                                               const ushort* __restrict__ blow,
                                               int* __restrict__ offs,
                                               int* __restrict__ list) {
  __shared__ int shist[512], sexcl[512], scur[512], wsum[8];
  __shared__ int stage[SMAX];
  const int b = blockIdx.x;
  const int t = threadIdx.x;
  const int base = bktbase[b];
  const int sb = b * CAP;               // staging base
  const int s = min(bktcnt[b], CAP);
  shist[t] = 0;
  __syncthreads();
  for (int e = t; e < s; e += 512) atomicAdd(&shist[blow[sb + e]], 1);
  __syncthreads();
  block_excl_scan_512(shist, sexcl, wsum);
  __syncthreads();
  int seg = (b << BKT_SHIFT) + t;
  if (seg < NT_SEG) offs[seg] = base + sexcl[t];
  scur[t] = sexcl[t];
  __syncthreads();
  if (s <= SMAX) {
    for (int e = t; e < s; e += 512) {
      int slot = atomicAdd(&scur[blow[sb + e]], 1);
      stage[slot] = bval[sb + e];
    }
    __syncthreads();
    for (int e = t; e < s; e += 512) list[base + e] = stage[e];
  } else {
    for (int e = t; e < s; e += 512) {
      int r = atomicAdd(&scur[blow[sb + e]], 1);
      list[base + r] = bval[sb + e];
    }
  }
}

// ---------- segment mean gather: DS-free, double-buffered index feed ----------
// 16 lanes/segment, uint4 row loads (256 B/row). Indices loaded as uniform
// per-lane global loads (HW broadcast) — no ds_bpermute anywhere in hot loop.
// Next chunk's 8 indices prefetched before accumulating current rows.
// MODE 0: write bf16 row. MODE 1: fused epilogue — +bias*gate, relu, fp32 out.
#define ACC8(V) do { \
    acc[0] += bf_lo(V.x); acc[1] += bf_hi(V.x); \
    acc[2] += bf_lo(V.y); acc[3] += bf_hi(V.y); \
    acc[4] += bf_lo(V.z); acc[5] += bf_hi(V.z); \
    acc[6] += bf_lo(V.w); acc[7] += bf_hi(V.w); } while (0)

template<int MODE>
__global__ __launch_bounds__(256) void k_agg(const ushort* __restrict__ src,
                                             void* __restrict__ dstv,
                                             const float* __restrict__ bias,
                                             const int* __restrict__ offs,
                                             const int* __restrict__ list,
                                             int nseg, int segbase) {
  int g = (int)((blockIdx.x * blockDim.x + threadIdx.x) >> 4);
  int t = threadIdx.x & 15;
  if (g >= nseg) return;
  int b0 = offs[segbase + g];
  int deg = offs[segbase + g + 1] - b0;
  float acc[8];
  #pragma unroll
  for (int j = 0; j < 8; ++j) acc[j] = 0.f;
  const int* lp = list + b0;
  // initial index load (uniform per group; may overread past segment — safe in ws)
  int ida[8];
  #pragma unroll
  for (int j = 0; j < 8; ++j) ida[j] = lp[j];
  int chunk = 0;
  while (chunk + 8 <= deg) {
    // issue 8 independent row loads (addresses depend only on landed ida)
    uint4 vb[8];
    #pragma unroll
    for (int j = 0; j < 8; ++j)
      vb[j] = reinterpret_cast<const uint4*>(src + (size_t)ida[j] * DD)[t];
    // prefetch next chunk's indices BEFORE consuming rows (stay in flight)
    int idb[8];
    #pragma unroll
    for (int j = 0; j < 8; ++j) idb[j] = lp[chunk + 8 + j];
    // accumulate (waits only on vb via in-order vmcnt; idb still outstanding)
    #pragma unroll
    for (int j = 0; j < 8; ++j) ACC8(vb[j]);
    #pragma unroll
    for (int j = 0; j < 8; ++j) ida[j] = idb[j];
    chunk += 8;
  }
  // tail: <=7 rows, indices already resident; loads exec-masked by the guard
  #pragma unroll
  for (int j = 0; j < 8; ++j) {
    if (chunk + j < deg) {
      uint4 v = reinterpret_cast<const uint4*>(src + (size_t)ida[j] * DD)[t];
      ACC8(v);
    }
  }
  float inv = 1.0f / fmaxf((float)deg, 1.0f);
  if (MODE == 0) {
    ushort* dst = (ushort*)dstv;
    uint4 o;
    o.x = (uint)f2bf(acc[0] * inv) | ((uint)f2bf(acc[1] * inv) << 16);
    o.y = (uint)f2bf(acc[2] * inv) | ((uint)f2bf(acc[3] * inv) << 16);
    o.z = (uint)f2bf(acc[4] * inv) | ((uint)f2bf(acc[5] * inv) << 16);
    o.w = (uint)f2bf(acc[6] * inv) | ((uint)f2bf(acc[7] * inv) << 16);
    reinterpret_cast<uint4*>(dst + (size_t)g * DD)[t] = o;
  } else {
    float flag = (deg > 0) ? 1.f : 0.f;
    float4 bb0 = reinterpret_cast<const float4*>(bias)[2 * t];
    float4 bb1 = reinterpret_cast<const float4*>(bias)[2 * t + 1];
    float4 o0, o1;
    o0.x = fmaxf(acc[0] * inv + bb0.x * flag, 0.f);
    o0.y = fmaxf(acc[1] * inv + bb0.y * flag, 0.f);
    o0.z = fmaxf(acc[2] * inv + bb0.z * flag, 0.f);
    o0.w = fmaxf(acc[3] * inv + bb0.w * flag, 0.f);
    o1.x = fmaxf(acc[4] * inv + bb1.x * flag, 0.f);
    o1.y = fmaxf(acc[5] * inv + bb1.y * flag, 0.f);
    o1.z = fmaxf(acc[6] * inv + bb1.z * flag, 0.f);
    o1.w = fmaxf(acc[7] * inv + bb1.w * flag, 0.f);
    float* orow = (float*)dstv + (size_t)g * DD;
    reinterpret_cast<float4*>(orow)[2 * t] = o0;
    reinterpret_cast<float4*>(orow)[2 * t + 1] = o1;
  }
}

// ---------- MFMA bf16 GEMM: C[M,128] = A[M,128] @ W (+ gated bias, relu) ----------
template<int RELU, int CBF16, int BIASED>
__global__ __launch_bounds__(256) void k_gemm_mfma(
    const ushort* __restrict__ A, void* __restrict__ Cv,
    const ushort* __restrict__ Wt, const float* __restrict__ bias,
    const int* __restrict__ segoff, int M) {
  __shared__ ushort sA[DD * DD];   // 32 KB, XOR-swizzled rows (256 B each)
  __shared__ ushort sW[DD * DD];   // 32 KB
  const int tid = threadIdx.x;
  const int R = blockIdx.x * DD;
  const int rows = min(DD, M - R);
  for (int i = tid; i < DD * 16; i += 256) {
    int r = i >> 4, c8 = i & 15;
    uint4 v = reinterpret_cast<const uint4*>(Wt + (size_t)r * DD)[c8];
    int bo = (c8 * 16) ^ ((r & 7) << 4);
    *reinterpret_cast<uint4*>(reinterpret_cast<char*>(sW) + r * 256 + bo) = v;
  }
  for (int i = tid; i < DD * 16; i += 256) {
    int r = i >> 4, c8 = i & 15;
    uint4 v = make_uint4(0u, 0u, 0u, 0u);
    if (r < rows) v = reinterpret_cast<const uint4*>(A + (size_t)(R + r) * DD)[c8];
    int bo = (c8 * 16) ^ ((r & 7) << 4);
    *reinterpret_cast<uint4*>(reinterpret_cast<char*>(sA) + r * 256 + bo) = v;
  }
  __syncthreads();
  const int wid = tid >> 6;
  const int l = tid & 63;
  const int lr = l & 15;
  const int lg = l >> 4;
  const int wrow = wid * 32;
  f32x4 acc[2][8];
  #pragma unroll
  for (int a = 0; a < 2; ++a)
    #pragma unroll
    for (int b = 0; b < 8; ++b) acc[a][b] = (f32x4){0.f, 0.f, 0.f, 0.f};
  const char* cA = reinterpret_cast<const char*>(sA);
  const char* cW = reinterpret_cast<const char*>(sW);
  #pragma unroll
  for (int k0 = 0; k0 < 4; ++k0) {
    int kb = k0 * 64 + lg * 16;
    int r0 = wrow + lr, r1 = wrow + 16 + lr;
    bf16x8 a0 = *reinterpret_cast<const bf16x8*>(cA + r0 * 256 + (kb ^ ((r0 & 7) << 4)));
    bf16x8 a1 = *reinterpret_cast<const bf16x8*>(cA + r1 * 256 + (kb ^ ((r1 & 7) << 4)));
    bf16x8 bfr[8];
    #pragma unroll
    for (int ct = 0; ct < 8; ++ct) {
      int c = ct * 16 + lr;
      bfr[ct] = *reinterpret_cast<const bf16x8*>(cW + c * 256 + (kb ^ ((c & 7) << 4)));
    }
    #pragma unroll
    for (int ct = 0; ct < 8; ++ct) {
      acc[0][ct] = __builtin_amdgcn_mfma_f32_16x16x32_bf16(a0, bfr[ct], acc[0][ct], 0, 0, 0);
      acc[1][ct] = __builtin_amdgcn_mfma_f32_16x16x32_bf16(a1, bfr[ct], acc[1][ct], 0, 0, 0);
    }
  }
  float bcol[8];
  if (BIASED) {
    #pragma unroll
    for (int ct = 0; ct < 8; ++ct) bcol[ct] = bias[ct * 16 + lr];
  }
  #pragma unroll
  for (int rt = 0; rt < 2; ++rt) {
    #pragma unroll
    for (int j = 0; j < 4; ++j) {
      int r = wrow + rt * 16 + lg * 4 + j;
      if (r < rows) {
        int gr = R + r;
        float flag = 0.f;
        if (BIASED) flag = (segoff[gr + 1] > segoff[gr]) ? 1.f : 0.f;
        #pragma unroll
        for (int ct = 0; ct < 8; ++ct) {
          float v = acc[rt][ct][j];
          if (BIASED) v += bcol[ct] * flag;
          if (RELU) v = fmaxf(v, 0.f);
          if (CBF16)
            reinterpret_cast<ushort*>(Cv)[(size_t)gr * DD + ct * 16 + lr] = f2bf(v);
          else
            reinterpret_cast<float*>(Cv)[(size_t)gr * DD + ct * 16 + lr] = v;
        }
      }
    }
  }
}

extern "C" void kernel_launch(void* const* d_in, const int* in_sizes, int n_in,
                              void* d_out, int out_size, void* d_ws, size_t ws_size,
                              hipStream_t stream) {
  const float* X   = (const float*)d_in[1];
  const int*   inc = (const int*)d_in[2];
  const float* W1  = (const float*)d_in[3];
  const float* b1  = (const float*)d_in[4];
  const float* W2  = (const float*)d_in[5];
  const float* b2  = (const float*)d_in[6];
  float* out = (float*)d_out;
  const int* ninc = inc;
  const int* einc = inc + NNZP;

  // workspace carve-up (~75 MB)
  char* wsp = (char*)d_ws;
  int* bval    = (int*)wsp;    wsp += (size_t)NBKT * CAP * sizeof(int);        // 24.0 MB staging vals
  ushort* blow = (ushort*)wsp; wsp += (size_t)NBKT * CAP * sizeof(ushort);     // 12.0 MB staging low9
  ushort* Xb   = (ushort*)wsp; wsp += (size_t)NN_NODES * DD * sizeof(ushort);  // 25.6 MB X bf16
  int* offs    = (int*)wsp;    wsp += (size_t)(NT_SEG + 1) * sizeof(int);      // 0.6 MB
  int* list    = (int*)wsp;    wsp += (size_t)TOTP * sizeof(int);              // 12.8 MB
  int* bktcur  = (int*)wsp;    wsp += 512 * sizeof(int);
  int* bktbase = (int*)wsp;    wsp += 512 * sizeof(int);
  ushort* Wct  = (ushort*)wsp; wsp += (size_t)DD * DD * sizeof(ushort);        // 32 KB
  float* bc    = (float*)wsp;  wsp += DD * sizeof(float);
  // E / E' buffer aliases the head of staging (staging dead after k_place)
  ushort* bufE = (ushort*)bval;                                                // 12.8 MB

  hipMemsetAsync(bktcur, 0, 512 * sizeof(int), stream);

  // Wc = W1@W2 (bf16 [c][k]), bc = b1@W2 + b2
  k_wc<<<16, 256, 0, stream>>>(W1, W2, b1, b2, Wct, bc);
  // bin into fixed-cap staging + fused X->bf16
  k_bin<<<NBIN + CVTBLK, 512, 0, stream>>>(ninc, einc, bktcur, bval, blow, X, Xb);
  // exact bucket bases from measured counts
  k_bscan<<<1, 512, 0, stream>>>(bktcur, bktbase, offs);
  // compact into final CSR (offs + list)
  k_place<<<NBKT, 512, 0, stream>>>(bktbase, bktcur, bval, blow, offs, list);

  // E[e] = mean_{n in e} Xb[n]  (bf16)
  k_agg<0><<<(NN_EDGES * 16 + 255) / 256, 256, 0, stream>>>(Xb, bufE, nullptr, offs, list, NN_EDGES, 0);
  // E' = E @ Wc  (50k rows, in-place bf16, MFMA, no bias)
  k_gemm_mfma<0, 1, 0><<<(NN_EDGES + DD - 1) / DD, 256, 0, stream>>>(bufE, bufE, Wct, nullptr, nullptr, NN_EDGES);
  // out[n] = relu(mean_{e ni n} E'[e] + bc*gate)  (fp32, fused epilogue)
  k_agg<1><<<(NN_NODES * 16 + 255) / 256, 256, 0, stream>>>(bufE, out, bc, offs, list, NN_NODES, NN_EDGES);
}

// Round 9
// 173.452 us; speedup vs baseline: 1.6516x; 1.1443x over previous
//
#include <hip/hip_runtime.h>

#define NN_NODES 100000
#define NN_EDGES 50000
#define DD 128
#define NNZP 1600000
#define NT_SEG (NN_EDGES + NN_NODES)   // 150000 segments (edges first, then nodes)
#define TOTP (2 * NNZP)                // 3.2M (seg,val) pairs across both directions
#define BKT_SHIFT 9                    // 512 segments per bucket
#define NBKT ((NT_SEG + 511) / 512)    // 293
#define TILE 8192
#define NBIN ((TOTP + TILE - 1) / TILE)  // 391
#define CVTBLK 1024
#define SMAX 18432
#define CAP 20480                      // fixed bucket staging capacity (~32 sigma margin)
#define VMASK 0xFFFFF                  // 20-bit value field in packed staging

typedef unsigned int uint;
typedef unsigned short ushort;
typedef __attribute__((ext_vector_type(8))) short bf16x8;
typedef __attribute__((ext_vector_type(4))) float f32x4;

__device__ __forceinline__ float bf_lo(uint u) {
  union { uint i; float f; } c; c.i = u << 16; return c.f;
}
__device__ __forceinline__ float bf_hi(uint u) {
  union { uint i; float f; } c; c.i = u & 0xffff0000u; return c.f;
}
__device__ __forceinline__ ushort f2bf(float f) {   // round-to-nearest-even
  union { float f; uint i; } c; c.f = f;
  uint r = c.i + 0x7fffu + ((c.i >> 16) & 1u);
  return (ushort)(r >> 16);
}

// ---------- exclusive block scan over 512 ints, 512 threads ----------
__device__ __forceinline__ void block_excl_scan_512(const int* __restrict__ arr,
                                                    int* __restrict__ out,
                                                    int* __restrict__ wsum) {
  int t = threadIdx.x;
  int v = arr[t];
  int lane = t & 63, wid = t >> 6;
  int s = v;
  #pragma unroll
  for (int o = 1; o < 64; o <<= 1) {
    int u = __shfl_up(s, o, 64);
    if (lane >= o) s += u;
  }
  if (lane == 63) wsum[wid] = s;
  __syncthreads();
  int add = 0;
  for (int w = 0; w < wid; ++w) add += wsum[w];
  out[t] = s + add - v;
}

// ---------- fused: bin pairs (packed staging) + X->bf16 + Wc/bc compose ----------
__global__ __launch_bounds__(512) void k_bin(const int* __restrict__ ninc,
                                             const int* __restrict__ einc,
                                             int* __restrict__ bktcur,
                                             int* __restrict__ pbuf,
                                             const float* __restrict__ X,
                                             ushort* __restrict__ Xb,
                                             const float* __restrict__ W1,
                                             const float* __restrict__ W2,
                                             const float* __restrict__ b1,
                                             const float* __restrict__ b2,
                                             ushort* __restrict__ Wct,
                                             float* __restrict__ bc) {
  __shared__ int spack[TILE];          // 32 KB (also reused as W1 stage in wc branch)
  __shared__ ushort sbkt[TILE];        // 16 KB
  __shared__ int bhist[512], bexcl[512], bcur[512], brun[512], wsum[8];
  const int b = blockIdx.x;
  const int t = threadIdx.x;
  if (b >= NBIN + CVTBLK) {
    // ---- Wc = W1@W2 (bf16 [c][k]) + bc = b1@W2 + b2 ----
    const int bb = b - NBIN - CVTBLK;  // 0..15, W1-rows [8bb, 8bb+8)
    float* sW1 = (float*)spack;        // 8x128 floats = 4 KB
    for (int i = t; i < 8 * 32; i += 512)
      reinterpret_cast<float4*>(sW1)[i] = reinterpret_cast<const float4*>(W1 + bb * 8 * DD)[i];
    __syncthreads();
    if (t < 256) {
      const int lr = t >> 5;           // local row 0..7
      const int cg = t & 31;           // col group (4 cols)
      float s0 = 0.f, s1 = 0.f, s2 = 0.f, s3 = 0.f;
      for (int j = 0; j < DD; ++j) {
        float a = sW1[lr * DD + j];
        float4 w = reinterpret_cast<const float4*>(W2)[j * 32 + cg];
        s0 += a * w.x; s1 += a * w.y; s2 += a * w.z; s3 += a * w.w;
      }
      const int grow = bb * 8 + lr;    // k-index in Wct[c][k]
      const int c0 = cg * 4;
      Wct[(size_t)(c0 + 0) * DD + grow] = f2bf(s0);
      Wct[(size_t)(c0 + 1) * DD + grow] = f2bf(s1);
      Wct[(size_t)(c0 + 2) * DD + grow] = f2bf(s2);
      Wct[(size_t)(c0 + 3) * DD + grow] = f2bf(s3);
    }
    if (bb == 0 && t >= 256 && t < 256 + DD) {
      int c = t - 256;
      float s = b2[c];
      for (int j = 0; j < DD; ++j) s += b1[j] * W2[(size_t)j * DD + c];
      bc[c] = s;
    }
    return;
  }
  if (b >= NBIN) {
    // ---- X -> bf16 convert (no syncthreads) ----
    const int stride = CVTBLK * 512;
    for (int i = (b - NBIN) * 512 + t; i < NN_NODES * DD / 4; i += stride) {
      float4 v = reinterpret_cast<const float4*>(X)[i];
      ushort4 o;
      o.x = f2bf(v.x); o.y = f2bf(v.y); o.z = f2bf(v.z); o.w = f2bf(v.w);
      reinterpret_cast<ushort4*>(Xb)[i] = o;
    }
    return;
  }
  // ---- binning ----
  const int i0 = b * TILE;
  const int V = min(TILE, TOTP - i0);
  int pseg[16], pval[16];
  bhist[t] = 0;
  __syncthreads();
  #pragma unroll
  for (int j = 0; j < 16; ++j) {
    int e = t + j * 512;
    if (e < V) {
      int i = i0 + e;
      int seg, val;
      if (i < NNZP) { seg = einc[i]; val = ninc[i]; }
      else          { seg = NN_EDGES + ninc[i - NNZP]; val = einc[i - NNZP]; }
      pseg[j] = seg; pval[j] = val;
      atomicAdd(&bhist[seg >> BKT_SHIFT], 1);
    }
  }
  __syncthreads();
  block_excl_scan_512(bhist, bexcl, wsum);
  __syncthreads();
  if (t < NBKT && bhist[t] > 0)
    brun[t] = t * CAP + atomicAdd(&bktcur[t], bhist[t]);
  bcur[t] = bexcl[t];
  __syncthreads();
  #pragma unroll
  for (int j = 0; j < 16; ++j) {
    int e = t + j * 512;
    if (e < V) {
      int bk = pseg[j] >> BKT_SHIFT;
      int slot = atomicAdd(&bcur[bk], 1);
      spack[slot] = ((pseg[j] & 511) << 20) | pval[j];
      sbkt[slot] = (ushort)bk;
    }
  }
  __syncthreads();
  for (int e = t; e < V; e += 512) {
    int bk = sbkt[e];
    int gpos = brun[bk] + (e - bexcl[bk]);
    if (gpos < (bk + 1) * CAP)           // OOB guard (statistically unreachable)
      pbuf[gpos] = spack[e];
  }
}

// ---------- per-bucket placement: inline base scan + offs + final list ----------
__global__ __launch_bounds__(512) void k_place(const int* __restrict__ bktcnt,
                                               const int* __restrict__ pbuf,
                                               int* __restrict__ offs,
                                               int* __restrict__ list) {
  __shared__ int shist[512], sexcl[512], scur[512], wsum[8], red[8];
  __shared__ int stage[SMAX];
  const int b = blockIdx.x;
  const int t = threadIdx.x;
  // base = sum_{i<b} min(cnt[i],CAP)
  int part = 0;
  for (int i = t; i < b; i += 512) part += min(bktcnt[i], CAP);
  #pragma unroll
  for (int o = 1; o < 64; o <<= 1) part += __shfl_xor(part, o, 64);
  if ((t & 63) == 0) red[t >> 6] = part;
  shist[t] = 0;
  __syncthreads();
  int base = 0;
  #pragma unroll
  for (int w = 0; w < 8; ++w) base += red[w];
  const int sb = b * CAP;
  const int s = min(bktcnt[b], CAP);
  for (int e = t; e < s; e += 512) atomicAdd(&shist[pbuf[sb + e] >> 20], 1);
  __syncthreads();
  block_excl_scan_512(shist, sexcl, wsum);
  __syncthreads();
  int seg = (b << BKT_SHIFT) + t;
  if (seg < NT_SEG) offs[seg] = base + sexcl[t];
  if (b == 0 && t == 0) offs[NT_SEG] = TOTP;
  scur[t] = sexcl[t];
  __syncthreads();
  if (s <= SMAX) {
    for (int e = t; e < s; e += 512) {
      int p = pbuf[sb + e];
      int slot = atomicAdd(&scur[p >> 20], 1);
      stage[slot] = p & VMASK;
    }
    __syncthreads();
    for (int e = t; e < s; e += 512) list[base + e] = stage[e];
  } else {
    for (int e = t; e < s; e += 512) {
      int p = pbuf[sb + e];
      int r = atomicAdd(&scur[p >> 20], 1);
      list[base + r] = p & VMASK;
    }
  }
}

// ---------- segment mean gather: DS-free, double-buffered index feed ----------
// 16 lanes/segment, uint4 row loads (256 B/row). Indices loaded as uniform
// per-lane global loads (HW broadcast). 8 rows + next 8 indices in flight.
// MODE 0: write bf16 row. MODE 1: fused epilogue — +bias*gate, relu, fp32 out.
#define ACC8(V) do { \
    acc[0] += bf_lo(V.x); acc[1] += bf_hi(V.x); \
    acc[2] += bf_lo(V.y); acc[3] += bf_hi(V.y); \
    acc[4] += bf_lo(V.z); acc[5] += bf_hi(V.z); \
    acc[6] += bf_lo(V.w); acc[7] += bf_hi(V.w); } while (0)

template<int MODE>
__global__ __launch_bounds__(256) void k_agg(const ushort* __restrict__ src,
                                             void* __restrict__ dstv,
                                             const float* __restrict__ bias,
                                             const int* __restrict__ offs,
                                             const int* __restrict__ list,
                                             int nseg, int segbase) {
  int g = (int)((blockIdx.x * blockDim.x + threadIdx.x) >> 4);
  int t = threadIdx.x & 15;
  if (g >= nseg) return;
  int b0 = offs[segbase + g];
  int deg = offs[segbase + g + 1] - b0;
  float acc[8];
  #pragma unroll
  for (int j = 0; j < 8; ++j) acc[j] = 0.f;
  const int* lp = list + b0;
  int ida[8];
  #pragma unroll
  for (int j = 0; j < 8; ++j) ida[j] = lp[j];
  int chunk = 0;
  while (chunk + 8 <= deg) {
    uint4 vb[8];
    #pragma unroll
    for (int j = 0; j < 8; ++j)
      vb[j] = reinterpret_cast<const uint4*>(src + (size_t)ida[j] * DD)[t];
    int idb[8];
    #pragma unroll
    for (int j = 0; j < 8; ++j) idb[j] = lp[chunk + 8 + j];
    #pragma unroll
    for (int j = 0; j < 8; ++j) ACC8(vb[j]);
    #pragma unroll
    for (int j = 0; j < 8; ++j) ida[j] = idb[j];
    chunk += 8;
  }
  if (chunk < deg) {
    uint4 vb[8];
    #pragma unroll
    for (int j = 0; j < 8; ++j) {
      uint4 v = make_uint4(0u, 0u, 0u, 0u);
      if (chunk + j < deg)
        v = reinterpret_cast<const uint4*>(src + (size_t)ida[j] * DD)[t];
      vb[j] = v;
    }
    #pragma unroll
    for (int j = 0; j < 8; ++j) ACC8(vb[j]);
  }
  float inv = 1.0f / fmaxf((float)deg, 1.0f);
  if (MODE == 0) {
    ushort* dst = (ushort*)dstv;
    uint4 o;
    o.x = (uint)f2bf(acc[0] * inv) | ((uint)f2bf(acc[1] * inv) << 16);
    o.y = (uint)f2bf(acc[2] * inv) | ((uint)f2bf(acc[3] * inv) << 16);
    o.z = (uint)f2bf(acc[4] * inv) | ((uint)f2bf(acc[5] * inv) << 16);
    o.w = (uint)f2bf(acc[6] * inv) | ((uint)f2bf(acc[7] * inv) << 16);
    reinterpret_cast<uint4*>(dst + (size_t)g * DD)[t] = o;
  } else {
    float flag = (deg > 0) ? 1.f : 0.f;
    float4 bb0 = reinterpret_cast<const float4*>(bias)[2 * t];
    float4 bb1 = reinterpret_cast<const float4*>(bias)[2 * t + 1];
    float4 o0, o1;
    o0.x = fmaxf(acc[0] * inv + bb0.x * flag, 0.f);
    o0.y = fmaxf(acc[1] * inv + bb0.y * flag, 0.f);
    o0.z = fmaxf(acc[2] * inv + bb0.z * flag, 0.f);
    o0.w = fmaxf(acc[3] * inv + bb0.w * flag, 0.f);
    o1.x = fmaxf(acc[4] * inv + bb1.x * flag, 0.f);
    o1.y = fmaxf(acc[5] * inv + bb1.y * flag, 0.f);
    o1.z = fmaxf(acc[6] * inv + bb1.z * flag, 0.f);
    o1.w = fmaxf(acc[7] * inv + bb1.w * flag, 0.f);
    float* orow = (float*)dstv + (size_t)g * DD;
    reinterpret_cast<float4*>(orow)[2 * t] = o0;
    reinterpret_cast<float4*>(orow)[2 * t + 1] = o1;
  }
}

// ---------- MFMA bf16 GEMM: C[M,128] = A[M,128] @ W (in-place, bf16 out) ----------
__global__ __launch_bounds__(256) void k_gemm_mfma(
    const ushort* __restrict__ A, ushort* __restrict__ C,
    const ushort* __restrict__ Wt, int M) {
  __shared__ ushort sA[DD * DD];   // 32 KB, XOR-swizzled rows (256 B each)
  __shared__ ushort sW[DD * DD];   // 32 KB
  const int tid = threadIdx.x;
  const int R = blockIdx.x * DD;
  const int rows = min(DD, M - R);
  for (int i = tid; i < DD * 16; i += 256) {
    int r = i >> 4, c8 = i & 15;
    uint4 v = reinterpret_cast<const uint4*>(Wt + (size_t)r * DD)[c8];
    int bo = (c8 * 16) ^ ((r & 7) << 4);
    *reinterpret_cast<uint4*>(reinterpret_cast<char*>(sW) + r * 256 + bo) = v;
  }
  for (int i = tid; i < DD * 16; i += 256) {
    int r = i >> 4, c8 = i & 15;
    uint4 v = make_uint4(0u, 0u, 0u, 0u);
    if (r < rows) v = reinterpret_cast<const uint4*>(A + (size_t)(R + r) * DD)[c8];
    int bo = (c8 * 16) ^ ((r & 7) << 4);
    *reinterpret_cast<uint4*>(reinterpret_cast<char*>(sA) + r * 256 + bo) = v;
  }
  __syncthreads();
  const int wid = tid >> 6;
  const int l = tid & 63;
  const int lr = l & 15;
  const int lg = l >> 4;
  const int wrow = wid * 32;
  f32x4 acc[2][8];
  #pragma unroll
  for (int a = 0; a < 2; ++a)
    #pragma unroll
    for (int b = 0; b < 8; ++b) acc[a][b] = (f32x4){0.f, 0.f, 0.f, 0.f};
  const char* cA = reinterpret_cast<const char*>(sA);
  const char* cW = reinterpret_cast<const char*>(sW);
  #pragma unroll
  for (int k0 = 0; k0 < 4; ++k0) {
    int kb = k0 * 64 + lg * 16;
    int r0 = wrow + lr, r1 = wrow + 16 + lr;
    bf16x8 a0 = *reinterpret_cast<const bf16x8*>(cA + r0 * 256 + (kb ^ ((r0 & 7) << 4)));
    bf16x8 a1 = *reinterpret_cast<const bf16x8*>(cA + r1 * 256 + (kb ^ ((r1 & 7) << 4)));
    bf16x8 bfr[8];
    #pragma unroll
    for (int ct = 0; ct < 8; ++ct) {
      int c = ct * 16 + lr;
      bfr[ct] = *reinterpret_cast<const bf16x8*>(cW + c * 256 + (kb ^ ((c & 7) << 4)));
    }
    #pragma unroll
    for (int ct = 0; ct < 8; ++ct) {
      acc[0][ct] = __builtin_amdgcn_mfma_f32_16x16x32_bf16(a0, bfr[ct], acc[0][ct], 0, 0, 0);
      acc[1][ct] = __builtin_amdgcn_mfma_f32_16x16x32_bf16(a1, bfr[ct], acc[1][ct], 0, 0, 0);
    }
  }
  #pragma unroll
  for (int rt = 0; rt < 2; ++rt) {
    #pragma unroll
    for (int j = 0; j < 4; ++j) {
      int r = wrow + rt * 16 + lg * 4 + j;
      if (r < rows) {
        int gr = R + r;
        #pragma unroll
        for (int ct = 0; ct < 8; ++ct)
          C[(size_t)gr * DD + ct * 16 + lr] = f2bf(acc[rt][ct][j]);
      }
    }
  }
}

extern "C" void kernel_launch(void* const* d_in, const int* in_sizes, int n_in,
                              void* d_out, int out_size, void* d_ws, size_t ws_size,
                              hipStream_t stream) {
  const float* X   = (const float*)d_in[1];
  const int*   inc = (const int*)d_in[2];
  const float* W1  = (const float*)d_in[3];
  const float* b1  = (const float*)d_in[4];
  const float* W2  = (const float*)d_in[5];
  const float* b2  = (const float*)d_in[6];
  float* out = (float*)d_out;
  const int* ninc = inc;
  const int* einc = inc + NNZP;

  // workspace carve-up (~63 MB)
  char* wsp = (char*)d_ws;
  int* pbuf    = (int*)wsp;    wsp += (size_t)NBKT * CAP * sizeof(int);        // 24.0 MB packed staging
  ushort* Xb   = (ushort*)wsp; wsp += (size_t)NN_NODES * DD * sizeof(ushort);  // 25.6 MB X bf16
  int* offs    = (int*)wsp;    wsp += (size_t)(NT_SEG + 1) * sizeof(int);      // 0.6 MB
  int* list    = (int*)wsp;    wsp += (size_t)TOTP * sizeof(int);              // 12.8 MB
  int* bktcur  = (int*)wsp;    wsp += 512 * sizeof(int);
  ushort* Wct  = (ushort*)wsp; wsp += (size_t)DD * DD * sizeof(ushort);        // 32 KB
  float* bc    = (float*)wsp;  wsp += DD * sizeof(float);
  // E / E' buffer aliases the head of staging (staging dead after k_place)
  ushort* bufE = (ushort*)pbuf;                                                // 12.8 MB

  hipMemsetAsync(bktcur, 0, 512 * sizeof(int), stream);

  // fused: bin into fixed-cap packed staging + X->bf16 + Wc/bc compose
  k_bin<<<NBIN + CVTBLK + 16, 512, 0, stream>>>(ninc, einc, bktcur, pbuf,
                                                X, Xb, W1, W2, b1, b2, Wct, bc);
  // compact into final CSR (offs + list), bucket bases computed inline
  k_place<<<NBKT, 512, 0, stream>>>(bktcur, pbuf, offs, list);

  // E[e] = mean_{n in e} Xb[n]  (bf16)
  k_agg<0><<<(NN_EDGES * 16 + 255) / 256, 256, 0, stream>>>(Xb, bufE, nullptr, offs, list, NN_EDGES, 0);
  // E' = E @ Wc  (50k rows, in-place bf16, MFMA)
  k_gemm_mfma<<<(NN_EDGES + DD - 1) / DD, 256, 0, stream>>>(bufE, bufE, Wct, NN_EDGES);
  // out[n] = relu(mean_{e ni n} E'[e] + bc*gate)  (fp32, fused epilogue)
  k_agg<1><<<(NN_NODES * 16 + 255) / 256, 256, 0, stream>>>(bufE, out, bc, offs, list, NN_NODES, NN_EDGES);
}